// Round 15
// baseline (527.299 us; speedup 1.0000x reference)
//
#include <hip/hip_runtime.h>
#include <hip/hip_bf16.h>

#define Tt   16384
#define Dd   1024
#define Ee   8
#define CAP  2048
#define DFFf 4096

typedef __attribute__((ext_vector_type(8))) short bf16x8;
typedef __attribute__((ext_vector_type(4))) float f32x4;

__device__ __forceinline__ unsigned short f2bf(float f) {
  union { float f; unsigned u; } v; v.f = f;
  unsigned r = (v.u + 0x7FFFu + ((v.u >> 16) & 1u)) >> 16;
  return (unsigned short)r;
}

__device__ __forceinline__ float gelu_tanh(float x) {
  float z = 0.7978845608028654f * (x + 0.044715f * x * x * x);
  float az = fabsf(z);
  float t = __expf(-2.0f * az);
  float th = (1.0f - t) / (1.0f + t);
  th = (z < 0.0f) ? -th : th;
  return 0.5f * x * (1.0f + th);
}

__device__ __forceinline__ void gld16(const void* g, void* l) {
  __builtin_amdgcn_global_load_lds(
      (const __attribute__((address_space(1))) void*)g,
      (__attribute__((address_space(3))) void*)l,
      16, 0, 0);
}

template <int IMM>
__device__ __forceinline__ bf16x8 dsr(unsigned a) {
  bf16x8 r;
  asm volatile("ds_read_b128 %0, %1 offset:%c2" : "=v"(r) : "v"(a), "i"(IMM));
  return r;
}
#define LGKM(N) asm volatile("s_waitcnt lgkmcnt(" #N ")" ::: "memory")
#define VMCNT(N) asm volatile("s_waitcnt vmcnt(" #N ")" ::: "memory")

// ---------------- gating: logits fp32, softmax, argmax ----------------
__global__ __launch_bounds__(256) void gating_kernel(
    const float* __restrict__ x, const float* __restrict__ wg,
    int* __restrict__ idx, float* __restrict__ gate, float* __restrict__ meP) {
  int tid = threadIdx.x, lane = tid & 63, w = tid >> 6;
  int t = blockIdx.x * 4 + w;
  const float* xr = x + (size_t)t * Dd;
  float p[8];
#pragma unroll
  for (int e2 = 0; e2 < 8; ++e2) p[e2] = 0.f;
#pragma unroll
  for (int i = 0; i < 16; ++i) {
    int j = lane + (i << 6);
    float xv = xr[j];
    const float4* wr = (const float4*)(wg + j * 8);
    float4 a = wr[0], b = wr[1];
    p[0] += xv * a.x; p[1] += xv * a.y; p[2] += xv * a.z; p[3] += xv * a.w;
    p[4] += xv * b.x; p[5] += xv * b.y; p[6] += xv * b.z; p[7] += xv * b.w;
  }
#pragma unroll
  for (int off = 32; off > 0; off >>= 1)
#pragma unroll
    for (int e2 = 0; e2 < 8; ++e2) p[e2] += __shfl_xor(p[e2], off);
  __shared__ float smG[4][8];
  if (lane == 0) {
    float mx = p[0]; int am = 0;
#pragma unroll
    for (int e2 = 1; e2 < 8; ++e2) if (p[e2] > mx) { mx = p[e2]; am = e2; }
    float s = 0.f, g2[8];
#pragma unroll
    for (int e2 = 0; e2 < 8; ++e2) { g2[e2] = __expf(p[e2] - mx); s += g2[e2]; }
    float inv = 1.f / s;
    idx[t] = am;
    gate[t] = g2[am] * inv;
#pragma unroll
    for (int e2 = 0; e2 < 8; ++e2) smG[w][e2] = g2[e2] * inv;
  }
  __syncthreads();
  if (tid < 8)
    meP[blockIdx.x * 8 + tid] = smG[0][tid] + smG[1][tid] + smG[2][tid] + smG[3][tid];
}

// ------------- parallel scan, stage 1: per-chunk expert counts -------------
__global__ __launch_bounds__(256) void count_kernel(
    const int* __restrict__ idx, int* __restrict__ cnt) {
  int tid = threadIdx.x, lane = tid & 63, w = tid >> 6;
  int e = idx[blockIdx.x * 256 + tid];
  __shared__ int c[4][8];
#pragma unroll
  for (int q = 0; q < 8; ++q) {
    unsigned long long m = __ballot(e == q);
    if (lane == 0) c[w][q] = (int)__popcll(m);
  }
  __syncthreads();
  if (tid < 8)
    cnt[blockIdx.x * 8 + tid] = c[0][tid] + c[1][tid] + c[2][tid] + c[3][tid];
}

// ------------- stage 2: exclusive prefix over chunks + l_aux + totals -------
__global__ __launch_bounds__(256) void prefix_kernel(
    const int* __restrict__ cnt, int* __restrict__ base,
    const float* __restrict__ meP, float* __restrict__ laux_out,
    int* __restrict__ etot) {
  int tid = threadIdx.x;
  __shared__ int tot[8];
  __shared__ float red[256];
  __shared__ float smes[8];
  if (tid < 8) {
    int run = 0;
    for (int b2 = 0; b2 < 64; ++b2) { base[b2 * 8 + tid] = run; run += cnt[b2 * 8 + tid]; }
    tot[tid] = run;
    etot[tid] = run;
  }
  float part = 0.f;
  int e2 = tid & 7, r0 = tid >> 3;
  for (int b2 = r0; b2 < 4096; b2 += 32) part += meP[b2 * 8 + e2];
  red[tid] = part;
  __syncthreads();
  if (tid < 8) {
    float s = 0.f;
    for (int i = 0; i < 32; ++i) s += red[i * 8 + tid];
    smes[tid] = s * (float)tot[tid];
  }
  __syncthreads();
  if (tid == 0) {
    float l = 0.f;
    for (int q = 0; q < 8; ++q) l += smes[q];
    laux_out[0] = l * 8.0f / ((float)Tt * (float)Tt);
  }
}

// ------------- stage 3: assign slots + fused dropped-row zeroing -------------
__global__ __launch_bounds__(256) void assign_kernel(
    const int* __restrict__ idx, const int* __restrict__ base,
    int* __restrict__ smap, float* __restrict__ out) {
  int tid = threadIdx.x, lane = tid & 63, w = tid >> 6;
  __shared__ int wc[4][8];
  __shared__ int dropN;
  __shared__ int dropL[256];
  if (tid == 0) dropN = 0;
  int t = blockIdx.x * 256 + tid;
  int e = idx[t];
  int myoff = 0;
#pragma unroll
  for (int q = 0; q < 8; ++q) {
    unsigned long long m = __ballot(e == q);
    if (lane == 0) wc[w][q] = (int)__popcll(m);
    if (e == q) myoff = (int)__popcll(m & ((1ull << lane) - 1ull));
  }
  __syncthreads();
  int b = base[blockIdx.x * 8 + e];
  for (int ww = 0; ww < w; ++ww) b += wc[ww][e];
  int p = b + myoff;
  if (p < CAP) {
    smap[e * CAP + p] = t;
  } else {
    int k = atomicAdd(&dropN, 1);
    dropL[k] = t;
  }
  __syncthreads();
  int nd = dropN;
  for (int k = 0; k < nd; ++k)
    ((float4*)(out + (size_t)dropL[k] * Dd))[tid] = make_float4(0.f, 0.f, 0.f, 0.f);
}

// ---- merged transpose + cast fp32 -> bf16; float4 loads, ushort4 stores ----
__global__ __launch_bounds__(256) void transpose_cast2(
    const float* __restrict__ w1, const float* __restrict__ w2,
    unsigned short* __restrict__ W1T, unsigned short* __restrict__ W2T) {
  __shared__ float tile[64][65];
  int z = blockIdx.z, tz = blockIdx.x;
  const float* s; unsigned short* d; int R, Cn, rb, cb;
  if (z < 8) {
    s = w1 + (size_t)z * Dd * DFFf; d = W1T + (size_t)z * Dd * DFFf;
    R = Dd; Cn = DFFf; rb = (tz >> 6) * 64; cb = (tz & 63) * 64;
  } else {
    s = w2 + (size_t)(z - 8) * DFFf * Dd; d = W2T + (size_t)(z - 8) * DFFf * Dd;
    R = DFFf; Cn = Dd; rb = (tz >> 4) * 64; cb = (tz & 15) * 64;
  }
  int tid = threadIdx.x;
  int c4 = (tid & 15) * 4;
  int r4 = tid >> 4;
#pragma unroll
  for (int i = 0; i < 4; ++i) {
    int r = r4 + i * 16;
    float4 v = *(const float4*)(s + (size_t)(rb + r) * Cn + cb + c4);
    tile[r][c4 + 0] = v.x; tile[r][c4 + 1] = v.y;
    tile[r][c4 + 2] = v.z; tile[r][c4 + 3] = v.w;
  }
  __syncthreads();
  int cc0 = (tid & 15) * 4;
  int rr0 = tid >> 4;
#pragma unroll
  for (int p = 0; p < 4; ++p) {
    int rr = rr0 + p * 16;
    ushort4 o;
    o.x = f2bf(tile[cc0 + 0][rr]);
    o.y = f2bf(tile[cc0 + 1][rr]);
    o.z = f2bf(tile[cc0 + 2][rr]);
    o.w = f2bf(tile[cc0 + 3][rr]);
    *(ushort4*)(d + (size_t)(cb + rr) * R + rb + cc0) = o;
  }
}

// ------------- gather + cast dispatched tokens (etot-guarded) -------------
__global__ __launch_bounds__(256) void build_xg(
    const float* __restrict__ x, const int* __restrict__ smap,
    const int* __restrict__ etot, unsigned short* __restrict__ Xg) {
  int row = blockIdx.x;
  int e = row >> 11, p = row & (CAP - 1);
  int t = (p < etot[e]) ? smap[row] : -1;
  int j = threadIdx.x;
  float4 v = make_float4(0.f, 0.f, 0.f, 0.f);
  if (t >= 0) v = ((const float4*)(x + (size_t)t * Dd))[j];
  ushort4 o;
  o.x = f2bf(v.x); o.y = f2bf(v.y); o.z = f2bf(v.z); o.w = f2bf(v.w);
  ((ushort4*)(Xg + (size_t)row * Dd))[j] = o;
}

// ---- 128^2-tile bf16 MFMA GEMM (B^T), BK=32 dbuf, 4 blocks/CU (m97 mech) ----
// 256 thr = 4 waves (2M x 2N), wave-tile 64x64 (acc[4][4] = 64 VGPR). LDS 32 KB
// (2 buf x {A 8K | B 8K}). Per tile: 4 gld16, 8 b128 reads (b0,b1,a0,a1 |
// b2,b3,a2,a3 with counted lgkm 4/0), 16 MFMA, ONE vmcnt(0)+barrier. The
// stage-drain stall is hidden by 3 other co-resident blocks (m114 TLP), not
// by in-block scheduling. Row-pair LDS layout (r8/r10-verified 0-conflict):
// line l holds rows 2l,2l+1; granule col = ((row&1)<<2) | (g ^ ((row>>1)&3)).
template <int DO_GELU, int FUSE_COMBINE>
__global__ __launch_bounds__(256, 4) void gemm128_kernel(
    const unsigned short* __restrict__ A,   // [E][M][K] bf16
    const unsigned short* __restrict__ BT,  // [E][N][K] bf16
    unsigned short* __restrict__ Hout,      // [E][M][N] bf16 (GEMM1)
    const int* __restrict__ smap,           // [E][CAP] token map (GEMM2)
    const int* __restrict__ etot,           // [E] expert totals (GEMM2)
    const float* __restrict__ gate,         // [T]
    float* __restrict__ out,                // [T][D]
    int M, int N, int K) {
  __shared__ char lds[32768];  // buf b at b*16384: [A 8K][B 8K]
  int tid = threadIdx.x, lane = tid & 63, w = tid >> 6;
  int wm = w >> 1, wn = w & 1;

  // bijective XCD-aware swizzle (nwg % 8 == 0); bn fastest (A-panel reuse)
  int gx = gridDim.x, gy = gridDim.y;
  long gid = blockIdx.x + (long)gx * (blockIdx.y + (long)gy * blockIdx.z);
  int nT = gx * gy * (int)gridDim.z;
  int cpx = nT >> 3;
  int swz = (int)((gid & 7) * (long)cpx + (gid >> 3));
  int bn = swz % gx;
  int bm = (swz / gx) % gy;
  int e  = swz / (gx * gy);

  const char* Ab = (const char*)(A + ((size_t)e * M + (size_t)bm * 128) * K);
  const char* Bb = (const char*)(BT + ((size_t)e * N + (size_t)bn * 128) * K);
  int K2 = K * 2;

  // staging source offsets (thread-const): region phys p -> (row, granule)
  unsigned sv0, sv1;
  {
    int p = tid * 16, ln = p >> 7, cl = (p >> 4) & 7;
    sv0 = (unsigned)((2 * ln + (cl >> 2)) * K2 + (((cl & 3) ^ (ln & 3)) << 4));
    p = 4096 + tid * 16; ln = p >> 7; cl = (p >> 4) & 7;
    sv1 = (unsigned)((2 * ln + (cl >> 2)) * K2 + (((cl & 3) ^ (ln & 3)) << 4));
  }
  char* dstB = (char*)lds + tid * 16;

#define STAGE(BUF, T) { \
    const char* As_ = Ab + (unsigned)(T) * 64u; \
    const char* Bs_ = Bb + (unsigned)(T) * 64u; \
    char* d_ = dstB + (BUF) * 16384; \
    gld16(As_ + sv0, d_); gld16(As_ + sv1, d_ + 4096); \
    gld16(Bs_ + sv0, d_ + 8192); gld16(Bs_ + sv1, d_ + 12288); }

  // fragment bases (buf0); +16 rows = +1024 B imm; buf swap via ^16384
  unsigned lb = (unsigned)(size_t)(__attribute__((address_space(3))) char*)lds;
  int arow = wm * 64 + (lane & 15);
  int brow = wn * 64 + (lane & 15);
  unsigned kg = (unsigned)(lane >> 4);
  unsigned aAd = lb + (unsigned)((arow >> 1) * 128 +
                 ((((arow & 1) << 2) | (kg ^ ((unsigned)(arow >> 1) & 3u))) << 4));
  unsigned bAd = lb + 8192u + (unsigned)((brow >> 1) * 128 +
                 ((((brow & 1) << 2) | (kg ^ ((unsigned)(brow >> 1) & 3u))) << 4));

  f32x4 acc[4][4];
#pragma unroll
  for (int mi = 0; mi < 4; ++mi)
#pragma unroll
    for (int n = 0; n < 4; ++n) acc[mi][n] = (f32x4){0.f, 0.f, 0.f, 0.f};

#define SB0 __builtin_amdgcn_sched_barrier(0)
#define MF(AV, MI_, BV, N_) acc[MI_][N_] = \
    __builtin_amdgcn_mfma_f32_16x16x32_bf16(AV, BV, acc[MI_][N_], 0, 0, 0)

  int NTk = K >> 5;  // BK = 32
  STAGE(0, 0)
  VMCNT(0);
  __builtin_amdgcn_s_barrier();

  for (int t = 0; t < NTk; ++t) {
    bool pf = (t + 1 < NTk);
    if (pf) STAGE((t & 1) ^ 1, t + 1)
    bf16x8 b0, b1, b2, b3, a0, a1, a2, a3;
    // interleaved issue: first 4 = {b0,b1,a0,a1}, last 4 = {b2,b3,a2,a3}
    b0 = dsr<0>(bAd); b1 = dsr<1024>(bAd);
    a0 = dsr<0>(aAd); a1 = dsr<1024>(aAd);
    b2 = dsr<2048>(bAd); b3 = dsr<3072>(bAd);
    a2 = dsr<2048>(aAd); a3 = dsr<3072>(aAd);
    LGKM(4); SB0;
    __builtin_amdgcn_s_setprio(1);
    MF(a0, 0, b0, 0); MF(a0, 0, b1, 1); MF(a1, 1, b0, 0); MF(a1, 1, b1, 1);
    __builtin_amdgcn_s_setprio(0);
    LGKM(0); SB0;
    __builtin_amdgcn_s_setprio(1);
    MF(a0, 0, b2, 2); MF(a0, 0, b3, 3); MF(a1, 1, b2, 2); MF(a1, 1, b3, 3);
    MF(a2, 2, b0, 0); MF(a2, 2, b1, 1); MF(a2, 2, b2, 2); MF(a2, 2, b3, 3);
    MF(a3, 3, b0, 0); MF(a3, 3, b1, 1); MF(a3, 3, b2, 2); MF(a3, 3, b3, 3);
    __builtin_amdgcn_s_setprio(0);
    if (pf) {
      VMCNT(0);
      __builtin_amdgcn_s_barrier();
      aAd ^= 16384u; bAd ^= 16384u;
    }
  }
#undef MF
#undef SB0
#undef STAGE

  // ---- epilogue ----
  int r0 = bm * 128 + wm * 64;
  int c0 = bn * 128 + wn * 64;
#pragma unroll
  for (int mi = 0; mi < 4; ++mi) {
    int rowb = r0 + mi * 16 + ((lane >> 4) << 2);
#pragma unroll
    for (int r = 0; r < 4; ++r) {
      int row = rowb + r;
      if (DO_GELU) {
#pragma unroll
        for (int n = 0; n < 4; ++n) {
          int col = c0 + n * 16 + (lane & 15);
          Hout[((size_t)e * M + row) * N + col] = f2bf(gelu_tanh(acc[mi][n][r]));
        }
      }
      if (FUSE_COMBINE) {
        int tkn = (row < etot[e]) ? smap[e * CAP + row] : -1;
        if (tkn >= 0) {
          float g = gate[tkn];
#pragma unroll
          for (int n = 0; n < 4; ++n) {
            int col = c0 + n * 16 + (lane & 15);
            out[(size_t)tkn * Dd + col] = acc[mi][n][r] * g;
          }
        }
      }
    }
  }
}

extern "C" void kernel_launch(void* const* d_in, const int* in_sizes, int n_in,
                              void* d_out, int out_size, void* d_ws, size_t ws_size,
                              hipStream_t stream) {
  const float* x  = (const float*)d_in[0];
  const float* wg = (const float*)d_in[1];
  const float* w1 = (const float*)d_in[2];
  const float* w2 = (const float*)d_in[3];
  float* out = (float*)d_out;

  char* ws = (char*)d_ws;
  int*   idx  = (int*)(ws + 0);
  float* gate = (float*)(ws + 131072);
  float* meP  = (float*)(ws + 196608);
  int*   smap = (int*)(ws + 327680);
  int*   cnt  = (int*)(ws + 393216);
  int*   base = (int*)(ws + 395264);
  int*   etot = (int*)(ws + 397312);
  unsigned short* Xg  = (unsigned short*)(ws + 401408ull);
  unsigned short* W1T = (unsigned short*)(ws + 33955840ull);
  unsigned short* W2T = (unsigned short*)(ws + 101064704ull);
  unsigned short* H   = (unsigned short*)(ws + 168173568ull);

  gating_kernel<<<Tt / 4, 256, 0, stream>>>(x, wg, idx, gate, meP);
  count_kernel<<<Tt / 256, 256, 0, stream>>>(idx, cnt);
  prefix_kernel<<<1, 256, 0, stream>>>(cnt, base, meP, out + (size_t)Tt * Dd, etot);
  assign_kernel<<<Tt / 256, 256, 0, stream>>>(idx, base, smap, out);
  transpose_cast2<<<dim3(1024, 1, 16), 256, 0, stream>>>(w1, w2, W1T, W2T);
  build_xg<<<Ee * CAP, 256, 0, stream>>>(x, smap, etot, Xg);
  gemm128_kernel<1, 0><<<dim3(DFFf / 128, CAP / 128, Ee), 256, 0, stream>>>(
      Xg, W1T, H, nullptr, nullptr, nullptr, nullptr, CAP, DFFf, Dd);
  gemm128_kernel<0, 1><<<dim3(Dd / 128, CAP / 128, Ee), 256, 0, stream>>>(
      H, W2T, nullptr, smap, etot, gate, out, CAP, Dd, DFFf);
}

// Round 16
// 460.135 us; speedup vs baseline: 1.1460x; 1.1460x over previous
//
#include <hip/hip_runtime.h>
#include <hip/hip_bf16.h>

#define Tt   16384
#define Dd   1024
#define Ee   8
#define CAP  2048
#define DFFf 4096

typedef __attribute__((ext_vector_type(8))) short bf16x8;
typedef __attribute__((ext_vector_type(4))) float f32x4;

__device__ __forceinline__ unsigned short f2bf(float f) {
  union { float f; unsigned u; } v; v.f = f;
  unsigned r = (v.u + 0x7FFFu + ((v.u >> 16) & 1u)) >> 16;
  return (unsigned short)r;
}

__device__ __forceinline__ float gelu_tanh(float x) {
  float z = 0.7978845608028654f * (x + 0.044715f * x * x * x);
  float az = fabsf(z);
  float t = __expf(-2.0f * az);
  float th = (1.0f - t) / (1.0f + t);
  th = (z < 0.0f) ? -th : th;
  return 0.5f * x * (1.0f + th);
}

__device__ __forceinline__ void gld16(const void* g, void* l) {
  __builtin_amdgcn_global_load_lds(
      (const __attribute__((address_space(1))) void*)g,
      (__attribute__((address_space(3))) void*)l,
      16, 0, 0);
}

template <int IMM>
__device__ __forceinline__ bf16x8 dsr(unsigned a) {
  bf16x8 r;
  asm volatile("ds_read_b128 %0, %1 offset:%c2" : "=v"(r) : "v"(a), "i"(IMM));
  return r;
}
#define LGKM(N) asm volatile("s_waitcnt lgkmcnt(" #N ")" ::: "memory")
#define VMCNT(N) asm volatile("s_waitcnt vmcnt(" #N ")" ::: "memory")

// ---------------- gating: logits fp32, softmax, argmax ----------------
__global__ __launch_bounds__(256) void gating_kernel(
    const float* __restrict__ x, const float* __restrict__ wg,
    int* __restrict__ idx, float* __restrict__ gate, float* __restrict__ meP) {
  int tid = threadIdx.x, lane = tid & 63, w = tid >> 6;
  int t = blockIdx.x * 4 + w;
  const float* xr = x + (size_t)t * Dd;
  float p[8];
#pragma unroll
  for (int e2 = 0; e2 < 8; ++e2) p[e2] = 0.f;
#pragma unroll
  for (int i = 0; i < 16; ++i) {
    int j = lane + (i << 6);
    float xv = xr[j];
    const float4* wr = (const float4*)(wg + j * 8);
    float4 a = wr[0], b = wr[1];
    p[0] += xv * a.x; p[1] += xv * a.y; p[2] += xv * a.z; p[3] += xv * a.w;
    p[4] += xv * b.x; p[5] += xv * b.y; p[6] += xv * b.z; p[7] += xv * b.w;
  }
#pragma unroll
  for (int off = 32; off > 0; off >>= 1)
#pragma unroll
    for (int e2 = 0; e2 < 8; ++e2) p[e2] += __shfl_xor(p[e2], off);
  __shared__ float smG[4][8];
  if (lane == 0) {
    float mx = p[0]; int am = 0;
#pragma unroll
    for (int e2 = 1; e2 < 8; ++e2) if (p[e2] > mx) { mx = p[e2]; am = e2; }
    float s = 0.f, g2[8];
#pragma unroll
    for (int e2 = 0; e2 < 8; ++e2) { g2[e2] = __expf(p[e2] - mx); s += g2[e2]; }
    float inv = 1.f / s;
    idx[t] = am;
    gate[t] = g2[am] * inv;
#pragma unroll
    for (int e2 = 0; e2 < 8; ++e2) smG[w][e2] = g2[e2] * inv;
  }
  __syncthreads();
  if (tid < 8)
    meP[blockIdx.x * 8 + tid] = smG[0][tid] + smG[1][tid] + smG[2][tid] + smG[3][tid];
}

// ------------- parallel scan, stage 1: per-chunk expert counts -------------
__global__ __launch_bounds__(256) void count_kernel(
    const int* __restrict__ idx, int* __restrict__ cnt) {
  int tid = threadIdx.x, lane = tid & 63, w = tid >> 6;
  int e = idx[blockIdx.x * 256 + tid];
  __shared__ int c[4][8];
#pragma unroll
  for (int q = 0; q < 8; ++q) {
    unsigned long long m = __ballot(e == q);
    if (lane == 0) c[w][q] = (int)__popcll(m);
  }
  __syncthreads();
  if (tid < 8)
    cnt[blockIdx.x * 8 + tid] = c[0][tid] + c[1][tid] + c[2][tid] + c[3][tid];
}

// ------------- stage 2: exclusive prefix over chunks + l_aux + totals -------
__global__ __launch_bounds__(256) void prefix_kernel(
    const int* __restrict__ cnt, int* __restrict__ base,
    const float* __restrict__ meP, float* __restrict__ laux_out,
    int* __restrict__ etot) {
  int tid = threadIdx.x;
  __shared__ int tot[8];
  __shared__ float red[256];
  __shared__ float smes[8];
  if (tid < 8) {
    int run = 0;
    for (int b2 = 0; b2 < 64; ++b2) { base[b2 * 8 + tid] = run; run += cnt[b2 * 8 + tid]; }
    tot[tid] = run;
    etot[tid] = run;
  }
  float part = 0.f;
  int e2 = tid & 7, r0 = tid >> 3;
  for (int b2 = r0; b2 < 4096; b2 += 32) part += meP[b2 * 8 + e2];
  red[tid] = part;
  __syncthreads();
  if (tid < 8) {
    float s = 0.f;
    for (int i = 0; i < 32; ++i) s += red[i * 8 + tid];
    smes[tid] = s * (float)tot[tid];
  }
  __syncthreads();
  if (tid == 0) {
    float l = 0.f;
    for (int q = 0; q < 8; ++q) l += smes[q];
    laux_out[0] = l * 8.0f / ((float)Tt * (float)Tt);
  }
}

// ------------- stage 3: assign slots + fused dropped-row zeroing -------------
__global__ __launch_bounds__(256) void assign_kernel(
    const int* __restrict__ idx, const int* __restrict__ base,
    int* __restrict__ smap, float* __restrict__ out) {
  int tid = threadIdx.x, lane = tid & 63, w = tid >> 6;
  __shared__ int wc[4][8];
  __shared__ int dropN;
  __shared__ int dropL[256];
  if (tid == 0) dropN = 0;
  int t = blockIdx.x * 256 + tid;
  int e = idx[t];
  int myoff = 0;
#pragma unroll
  for (int q = 0; q < 8; ++q) {
    unsigned long long m = __ballot(e == q);
    if (lane == 0) wc[w][q] = (int)__popcll(m);
    if (e == q) myoff = (int)__popcll(m & ((1ull << lane) - 1ull));
  }
  __syncthreads();
  int b = base[blockIdx.x * 8 + e];
  for (int ww = 0; ww < w; ++ww) b += wc[ww][e];
  int p = b + myoff;
  if (p < CAP) {
    smap[e * CAP + p] = t;
  } else {
    int k = atomicAdd(&dropN, 1);
    dropL[k] = t;
  }
  __syncthreads();
  int nd = dropN;
  for (int k = 0; k < nd; ++k)
    ((float4*)(out + (size_t)dropL[k] * Dd))[tid] = make_float4(0.f, 0.f, 0.f, 0.f);
}

// ---- merged transpose + cast fp32 -> bf16; float4 loads, ushort4 stores ----
__global__ __launch_bounds__(256) void transpose_cast2(
    const float* __restrict__ w1, const float* __restrict__ w2,
    unsigned short* __restrict__ W1T, unsigned short* __restrict__ W2T) {
  __shared__ float tile[64][65];
  int z = blockIdx.z, tz = blockIdx.x;
  const float* s; unsigned short* d; int R, Cn, rb, cb;
  if (z < 8) {
    s = w1 + (size_t)z * Dd * DFFf; d = W1T + (size_t)z * Dd * DFFf;
    R = Dd; Cn = DFFf; rb = (tz >> 6) * 64; cb = (tz & 63) * 64;
  } else {
    s = w2 + (size_t)(z - 8) * DFFf * Dd; d = W2T + (size_t)(z - 8) * DFFf * Dd;
    R = DFFf; Cn = Dd; rb = (tz >> 4) * 64; cb = (tz & 15) * 64;
  }
  int tid = threadIdx.x;
  int c4 = (tid & 15) * 4;
  int r4 = tid >> 4;
#pragma unroll
  for (int i = 0; i < 4; ++i) {
    int r = r4 + i * 16;
    float4 v = *(const float4*)(s + (size_t)(rb + r) * Cn + cb + c4);
    tile[r][c4 + 0] = v.x; tile[r][c4 + 1] = v.y;
    tile[r][c4 + 2] = v.z; tile[r][c4 + 3] = v.w;
  }
  __syncthreads();
  int cc0 = (tid & 15) * 4;
  int rr0 = tid >> 4;
#pragma unroll
  for (int p = 0; p < 4; ++p) {
    int rr = rr0 + p * 16;
    ushort4 o;
    o.x = f2bf(tile[cc0 + 0][rr]);
    o.y = f2bf(tile[cc0 + 1][rr]);
    o.z = f2bf(tile[cc0 + 2][rr]);
    o.w = f2bf(tile[cc0 + 3][rr]);
    *(ushort4*)(d + (size_t)(cb + rr) * R + rb + cc0) = o;
  }
}

// ------------- gather + cast dispatched tokens (etot-guarded) -------------
__global__ __launch_bounds__(256) void build_xg(
    const float* __restrict__ x, const int* __restrict__ smap,
    const int* __restrict__ etot, unsigned short* __restrict__ Xg) {
  int row = blockIdx.x;
  int e = row >> 11, p = row & (CAP - 1);
  int t = (p < etot[e]) ? smap[row] : -1;
  int j = threadIdx.x;
  float4 v = make_float4(0.f, 0.f, 0.f, 0.f);
  if (t >= 0) v = ((const float4*)(x + (size_t)t * Dd))[j];
  ushort4 o;
  o.x = f2bf(v.x); o.y = f2bf(v.y); o.z = f2bf(v.z); o.w = f2bf(v.w);
  ((ushort4*)(Xg + (size_t)row * Dd))[j] = o;
}

// ------------- 256^2-tile bf16 MFMA GEMM (B^T), counted-vmcnt dbuf (r6) -----
// 8 waves (2M x 4N), per-wave 128x64, BK=64, dbuf LDS, 0-conflict XOR layout.
// Staging split P0/P1/P2; waits vmcnt(4)@P1 (>=2-phase cover), vmcnt(2)@P3;
// never 0 in steady loop. ds_read groups pipelined with counted lgkm 8/4/4/0.
// Converged config: 810 TF = 90% of the 2-barrier-structure ceiling (m97/m131-141).
template <int DO_GELU, int FUSE_COMBINE>
__global__ __launch_bounds__(512, 2) void gemm256_kernel(
    const unsigned short* __restrict__ A,   // [E][M][K] bf16
    const unsigned short* __restrict__ BT,  // [E][N][K] bf16
    unsigned short* __restrict__ Hout,      // [E][M][N] bf16 (GEMM1)
    const int* __restrict__ smap,           // [E][CAP] token map (GEMM2)
    const int* __restrict__ etot,           // [E] expert totals (GEMM2)
    const float* __restrict__ gate,         // [T]
    float* __restrict__ out,                // [T][D]
    int M, int N, int K) {
  __shared__ unsigned short lds[2][2][16384];  // [buf][A/B][256 rows x 64 k]
  int tid = threadIdx.x, lane = tid & 63, w = tid >> 6;
  int wm = w >> 2, wn = w & 3;

  // bijective XCD-aware swizzle (nwg % 8 == 0)
  int gx = gridDim.x, gy = gridDim.y;
  long gid = blockIdx.x + (long)gx * (blockIdx.y + (long)gy * blockIdx.z);
  int nT = gx * gy * (int)gridDim.z;
  int cpx = nT >> 3;
  int swz = (int)((gid & 7) * (long)cpx + (gid >> 3));
  int bn = swz % gx;
  int bm = (swz / gx) % gy;
  int e  = swz / (gx * gy);

  const unsigned short* Ab = A + ((size_t)e * M + (size_t)bm * 256) * K;
  const unsigned short* Bb = BT + ((size_t)e * N + (size_t)bn * 256) * K;

  // phys p holds logical p ^ (((p>>7)&7)<<4) (involution, both-sides swizzle)
  auto stageB = [&](const unsigned short* src, unsigned short* L, int h) {
#pragma unroll
    for (int q = 0; q < 2; ++q) {
      int p = h * 16384 + q * 8192 + tid * 16;
      int lg = p ^ (((p >> 7) & 7) << 4);
      gld16(src + (size_t)(lg >> 7) * K + ((lg & 127) >> 1),
            (unsigned short*)((char*)L + p));
    }
  };
  auto stageA = [&](const unsigned short* src, unsigned short* L, int h) {
#pragma unroll
    for (int q = 0; q < 2; ++q) {
      int p = q * 16384 + h * 8192 + tid * 16;
      int lg = p ^ (((p >> 7) & 7) << 4);
      gld16(src + (size_t)(lg >> 7) * K + ((lg & 127) >> 1),
            (unsigned short*)((char*)L + p));
    }
  };

  f32x4 acc[2][4][4];
#pragma unroll
  for (int mh = 0; mh < 2; ++mh)
#pragma unroll
    for (int mi = 0; mi < 4; ++mi)
#pragma unroll
      for (int n = 0; n < 4; ++n) acc[mh][mi][n] = (f32x4){0.f, 0.f, 0.f, 0.f};

  auto mfma16 = [&](f32x4 (*ac)[4], const bf16x8* av, const bf16x8* bv) {
#pragma unroll
    for (int mi = 0; mi < 4; ++mi)
#pragma unroll
      for (int n = 0; n < 4; ++n)
        ac[mi][n] = __builtin_amdgcn_mfma_f32_16x16x32_bf16(av[mi], bv[n], ac[mi][n], 0, 0, 0);
  };

  unsigned lbase = (unsigned)(size_t)(__attribute__((address_space(3))) unsigned short*)&lds[0][0][0];
  int arow = wm * 128 + (lane & 15);
  int brow = wn * 64 + (lane & 15);
  unsigned kc2 = (unsigned)(((lane >> 4) << 3) << 1);
  unsigned swA = (unsigned)((arow & 7) << 4), swB = (unsigned)((brow & 7) << 4);
  unsigned ak0 = lbase + ((((unsigned)arow << 7) + kc2) ^ swA);
  unsigned ak1 = lbase + ((((unsigned)arow << 7) + 64 + kc2) ^ swA);
  unsigned bk0 = lbase + 32768u + ((((unsigned)brow << 7) + kc2) ^ swB);
  unsigned bk1 = lbase + 32768u + ((((unsigned)brow << 7) + 64 + kc2) ^ swB);

  bf16x8 a0[4], a1[4], a2[4], a3[4], b0[4], b1[4];
#define G0_ { \
    b0[0] = dsr<0>(bk0); b0[1] = dsr<2048>(bk0); b0[2] = dsr<4096>(bk0); b0[3] = dsr<6144>(bk0); \
    a0[0] = dsr<0>(ak0); a0[1] = dsr<2048>(ak0); a0[2] = dsr<4096>(ak0); a0[3] = dsr<6144>(ak0); }
#define G1_ { \
    b1[0] = dsr<0>(bk1); b1[1] = dsr<2048>(bk1); b1[2] = dsr<4096>(bk1); b1[3] = dsr<6144>(bk1); \
    a1[0] = dsr<0>(ak1); a1[1] = dsr<2048>(ak1); a1[2] = dsr<4096>(ak1); a1[3] = dsr<6144>(ak1); }
#define G2_ { \
    a2[0] = dsr<8192>(ak0); a2[1] = dsr<10240>(ak0); a2[2] = dsr<12288>(ak0); a2[3] = dsr<14336>(ak0); }
#define G3_ { \
    a3[0] = dsr<8192>(ak1); a3[1] = dsr<10240>(ak1); a3[2] = dsr<12288>(ak1); a3[3] = dsr<14336>(ak1); }
#define SB0 __builtin_amdgcn_sched_barrier(0)
#define PRIO_MFMA(AC, AV, BV) { \
    __builtin_amdgcn_s_setprio(1); mfma16(AC, AV, BV); __builtin_amdgcn_s_setprio(0); }

  int NT = K >> 6;
  stageB(Bb, lds[0][1], 0); stageB(Bb, lds[0][1], 1);
  stageA(Ab, lds[0][0], 0);
  stageA(Ab, lds[0][0], 1);
  VMCNT(2);
  __builtin_amdgcn_s_barrier();
  G0_

  for (int t = 0; t < NT - 1; ++t) {
    unsigned short* SA = lds[(t & 1) ^ 1][0];
    unsigned short* SB = lds[(t & 1) ^ 1][1];
    const unsigned short* An = Ab + ((t + 1) << 6);
    const unsigned short* Bn = Bb + ((t + 1) << 6);
    // ---- P0: reads G1; stage B(t+1); wait G0; MFMA a0xb0 ----
    G1_
    stageB(Bn, SB, 0); stageB(Bn, SB, 1);
    LGKM(8); SB0;
    PRIO_MFMA(acc[0], a0, b0);
    // ---- P1: drain A-h1(t); reads G2; stage A-h0(t+1); wait G1; MFMA a1xb1 ----
    VMCNT(4);
    __builtin_amdgcn_s_barrier();
    G2_
    stageA(An, SA, 0);
    LGKM(4); SB0;
    PRIO_MFMA(acc[0], a1, b1);
    // ---- P2: reads G3; stage A-h1(t+1); wait G2; MFMA a2xb0 ----
    G3_
    stageA(An, SA, 1);
    LGKM(4); SB0;
    PRIO_MFMA(acc[1], a2, b0);
    // ---- P3: wait G3; MFMA a3xb1; drain B+A-h0(t+1); swap; reads G0 ----
    LGKM(0); SB0;
    PRIO_MFMA(acc[1], a3, b1);
    VMCNT(2);
    __builtin_amdgcn_s_barrier();
    ak0 ^= 65536u; ak1 ^= 65536u; bk0 ^= 65536u; bk1 ^= 65536u;
    G0_
  }

  // ---- final tile: no staging; single vmcnt(0) at P1 ----
  G1_
  LGKM(8); SB0;
  PRIO_MFMA(acc[0], a0, b0);
  VMCNT(0);
  __builtin_amdgcn_s_barrier();
  G2_
  LGKM(4); SB0;
  PRIO_MFMA(acc[0], a1, b1);
  G3_
  LGKM(4); SB0;
  PRIO_MFMA(acc[1], a2, b0);
  LGKM(0); SB0;
  PRIO_MFMA(acc[1], a3, b1);

#undef G0_
#undef G1_
#undef G2_
#undef G3_
#undef SB0
#undef PRIO_MFMA

  // ---- epilogue ----
  int r0 = bm * 256 + wm * 128;
  int c0 = bn * 256 + wn * 64;
#pragma unroll
  for (int mh = 0; mh < 2; ++mh)
#pragma unroll
    for (int mi = 0; mi < 4; ++mi) {
      int rowb = r0 + mh * 64 + mi * 16 + ((lane >> 4) << 2);
#pragma unroll
      for (int r = 0; r < 4; ++r) {
        int row = rowb + r;
        if (DO_GELU) {
#pragma unroll
          for (int n = 0; n < 4; ++n) {
            int col = c0 + n * 16 + (lane & 15);
            Hout[((size_t)e * M + row) * N + col] = f2bf(gelu_tanh(acc[mh][mi][n][r]));
          }
        }
        if (FUSE_COMBINE) {
          int tkn = (row < etot[e]) ? smap[e * CAP + row] : -1;
          if (tkn >= 0) {
            float g = gate[tkn];
#pragma unroll
            for (int n = 0; n < 4; ++n) {
              int col = c0 + n * 16 + (lane & 15);
              out[(size_t)tkn * Dd + col] = acc[mh][mi][n][r] * g;
            }
          }
        }
      }
    }
}

extern "C" void kernel_launch(void* const* d_in, const int* in_sizes, int n_in,
                              void* d_out, int out_size, void* d_ws, size_t ws_size,
                              hipStream_t stream) {
  const float* x  = (const float*)d_in[0];
  const float* wg = (const float*)d_in[1];
  const float* w1 = (const float*)d_in[2];
  const float* w2 = (const float*)d_in[3];
  float* out = (float*)d_out;

  char* ws = (char*)d_ws;
  int*   idx  = (int*)(ws + 0);
  float* gate = (float*)(ws + 131072);
  float* meP  = (float*)(ws + 196608);
  int*   smap = (int*)(ws + 327680);
  int*   cnt  = (int*)(ws + 393216);
  int*   base = (int*)(ws + 395264);
  int*   etot = (int*)(ws + 397312);
  unsigned short* Xg  = (unsigned short*)(ws + 401408ull);
  unsigned short* W1T = (unsigned short*)(ws + 33955840ull);
  unsigned short* W2T = (unsigned short*)(ws + 101064704ull);
  unsigned short* H   = (unsigned short*)(ws + 168173568ull);

  gating_kernel<<<Tt / 4, 256, 0, stream>>>(x, wg, idx, gate, meP);
  count_kernel<<<Tt / 256, 256, 0, stream>>>(idx, cnt);
  prefix_kernel<<<1, 256, 0, stream>>>(cnt, base, meP, out + (size_t)Tt * Dd, etot);
  assign_kernel<<<Tt / 256, 256, 0, stream>>>(idx, base, smap, out);
  transpose_cast2<<<dim3(1024, 1, 16), 256, 0, stream>>>(w1, w2, W1T, W2T);
  build_xg<<<Ee * CAP, 256, 0, stream>>>(x, smap, etot, Xg);
  gemm256_kernel<1, 0><<<dim3(DFFf / 256, CAP / 256, Ee), 512, 0, stream>>>(
      Xg, W1T, H, nullptr, nullptr, nullptr, nullptr, CAP, DFFf, Dd);
  gemm256_kernel<0, 1><<<dim3(Dd / 256, CAP / 256, Ee), 512, 0, stream>>>(
      H, W2T, nullptr, smap, etot, gate, out, CAP, Dd, DFFf);
}

// Round 17
// 454.648 us; speedup vs baseline: 1.1598x; 1.0121x over previous
//
#include <hip/hip_runtime.h>
#include <hip/hip_bf16.h>

#define Tt   16384
#define Dd   1024
#define Ee   8
#define CAP  2048
#define DFFf 4096

typedef __attribute__((ext_vector_type(8))) short bf16x8;
typedef __attribute__((ext_vector_type(4))) float f32x4;

__device__ __forceinline__ unsigned short f2bf(float f) {
  union { float f; unsigned u; } v; v.f = f;
  unsigned r = (v.u + 0x7FFFu + ((v.u >> 16) & 1u)) >> 16;
  return (unsigned short)r;
}

__device__ __forceinline__ float gelu_tanh(float x) {
  float z = 0.7978845608028654f * (x + 0.044715f * x * x * x);
  float az = fabsf(z);
  float t = __expf(-2.0f * az);
  float th = (1.0f - t) / (1.0f + t);
  th = (z < 0.0f) ? -th : th;
  return 0.5f * x * (1.0f + th);
}

__device__ __forceinline__ void gld16(const void* g, void* l) {
  __builtin_amdgcn_global_load_lds(
      (const __attribute__((address_space(1))) void*)g,
      (__attribute__((address_space(3))) void*)l,
      16, 0, 0);
}

template <int IMM>
__device__ __forceinline__ bf16x8 dsr(unsigned a) {
  bf16x8 r;
  asm volatile("ds_read_b128 %0, %1 offset:%c2" : "=v"(r) : "v"(a), "i"(IMM));
  return r;
}
#define LGKM(N) asm volatile("s_waitcnt lgkmcnt(" #N ")" ::: "memory")
#define VMCNT(N) asm volatile("s_waitcnt vmcnt(" #N ")" ::: "memory")

// ---- gating (blocks 0..4095) + w1 transpose->W1T (blocks 4096..12287) ----
__global__ __launch_bounds__(256) void gating_w1t_kernel(
    const float* __restrict__ x, const float* __restrict__ wg,
    const float* __restrict__ w1,
    int* __restrict__ idx, float* __restrict__ gate, float* __restrict__ meP,
    unsigned short* __restrict__ W1T) {
  __shared__ float tileT[64][65];
  __shared__ float smG[4][8];
  int tid = threadIdx.x, lane = tid & 63, w = tid >> 6;

  if (blockIdx.x >= 4096) {
    // ---- w1 transpose tile: W1T[e][n][k] = w1[e][k][n], n over DFF, k over Dd
    int tz = blockIdx.x - 4096;          // 0..8191
    int ze = tz >> 10, tile = tz & 1023; // per expert: 16 row-tiles x 64 col-tiles
    const float* s = w1 + (size_t)ze * Dd * DFFf;
    unsigned short* d = W1T + (size_t)ze * Dd * DFFf;
    int rb = (tile >> 6) * 64, cb = (tile & 63) * 64;
    int c4 = (tid & 15) * 4;
    int r4 = tid >> 4;
#pragma unroll
    for (int i = 0; i < 4; ++i) {
      int r = r4 + i * 16;
      float4 v = *(const float4*)(s + (size_t)(rb + r) * DFFf + cb + c4);
      tileT[r][c4 + 0] = v.x; tileT[r][c4 + 1] = v.y;
      tileT[r][c4 + 2] = v.z; tileT[r][c4 + 3] = v.w;
    }
    __syncthreads();
#pragma unroll
    for (int p = 0; p < 4; ++p) {
      int rr = r4 + p * 16;
      ushort4 o;
      o.x = f2bf(tileT[c4 + 0][rr]);
      o.y = f2bf(tileT[c4 + 1][rr]);
      o.z = f2bf(tileT[c4 + 2][rr]);
      o.w = f2bf(tileT[c4 + 3][rr]);
      *(ushort4*)(d + (size_t)(cb + rr) * Dd + rb + c4) = o;
    }
    return;
  }

  // ---- gating path ----
  int t = blockIdx.x * 4 + w;
  const float* xr = x + (size_t)t * Dd;
  float p[8];
#pragma unroll
  for (int e2 = 0; e2 < 8; ++e2) p[e2] = 0.f;
#pragma unroll
  for (int i = 0; i < 16; ++i) {
    int j = lane + (i << 6);
    float xv = xr[j];
    const float4* wr = (const float4*)(wg + j * 8);
    float4 a = wr[0], b = wr[1];
    p[0] += xv * a.x; p[1] += xv * a.y; p[2] += xv * a.z; p[3] += xv * a.w;
    p[4] += xv * b.x; p[5] += xv * b.y; p[6] += xv * b.z; p[7] += xv * b.w;
  }
#pragma unroll
  for (int off = 32; off > 0; off >>= 1)
#pragma unroll
    for (int e2 = 0; e2 < 8; ++e2) p[e2] += __shfl_xor(p[e2], off);
  if (lane == 0) {
    float mx = p[0]; int am = 0;
#pragma unroll
    for (int e2 = 1; e2 < 8; ++e2) if (p[e2] > mx) { mx = p[e2]; am = e2; }
    float s = 0.f, g2[8];
#pragma unroll
    for (int e2 = 0; e2 < 8; ++e2) { g2[e2] = __expf(p[e2] - mx); s += g2[e2]; }
    float inv = 1.f / s;
    idx[t] = am;
    gate[t] = g2[am] * inv;
#pragma unroll
    for (int e2 = 0; e2 < 8; ++e2) smG[w][e2] = g2[e2] * inv;
  }
  __syncthreads();
  if (tid < 8)
    meP[blockIdx.x * 8 + tid] = smG[0][tid] + smG[1][tid] + smG[2][tid] + smG[3][tid];
}

// ------------- parallel scan, stage 1: per-chunk expert counts -------------
__global__ __launch_bounds__(256) void count_kernel(
    const int* __restrict__ idx, int* __restrict__ cnt) {
  int tid = threadIdx.x, lane = tid & 63, w = tid >> 6;
  int e = idx[blockIdx.x * 256 + tid];
  __shared__ int c[4][8];
#pragma unroll
  for (int q = 0; q < 8; ++q) {
    unsigned long long m = __ballot(e == q);
    if (lane == 0) c[w][q] = (int)__popcll(m);
  }
  __syncthreads();
  if (tid < 8)
    cnt[blockIdx.x * 8 + tid] = c[0][tid] + c[1][tid] + c[2][tid] + c[3][tid];
}

// ------------- stage 2: exclusive prefix over chunks + l_aux + totals -------
__global__ __launch_bounds__(256) void prefix_kernel(
    const int* __restrict__ cnt, int* __restrict__ base,
    const float* __restrict__ meP, float* __restrict__ laux_out,
    int* __restrict__ etot) {
  int tid = threadIdx.x;
  __shared__ int tot[8];
  __shared__ float red[256];
  __shared__ float smes[8];
  if (tid < 8) {
    int run = 0;
    for (int b2 = 0; b2 < 64; ++b2) { base[b2 * 8 + tid] = run; run += cnt[b2 * 8 + tid]; }
    tot[tid] = run;
    etot[tid] = run;
  }
  float part = 0.f;
  int e2 = tid & 7, r0 = tid >> 3;
  for (int b2 = r0; b2 < 4096; b2 += 32) part += meP[b2 * 8 + e2];
  red[tid] = part;
  __syncthreads();
  if (tid < 8) {
    float s = 0.f;
    for (int i = 0; i < 32; ++i) s += red[i * 8 + tid];
    smes[tid] = s * (float)tot[tid];
  }
  __syncthreads();
  if (tid == 0) {
    float l = 0.f;
    for (int q = 0; q < 8; ++q) l += smes[q];
    laux_out[0] = l * 8.0f / ((float)Tt * (float)Tt);
  }
}

// ------------- stage 3: assign slots + fused dropped-row zeroing -------------
__global__ __launch_bounds__(256) void assign_kernel(
    const int* __restrict__ idx, const int* __restrict__ base,
    int* __restrict__ smap, float* __restrict__ out) {
  int tid = threadIdx.x, lane = tid & 63, w = tid >> 6;
  __shared__ int wc[4][8];
  __shared__ int dropN;
  __shared__ int dropL[256];
  if (tid == 0) dropN = 0;
  int t = blockIdx.x * 256 + tid;
  int e = idx[t];
  int myoff = 0;
#pragma unroll
  for (int q = 0; q < 8; ++q) {
    unsigned long long m = __ballot(e == q);
    if (lane == 0) wc[w][q] = (int)__popcll(m);
    if (e == q) myoff = (int)__popcll(m & ((1ull << lane) - 1ull));
  }
  __syncthreads();
  int b = base[blockIdx.x * 8 + e];
  for (int ww = 0; ww < w; ++ww) b += wc[ww][e];
  int p = b + myoff;
  if (p < CAP) {
    smap[e * CAP + p] = t;
  } else {
    int k = atomicAdd(&dropN, 1);
    dropL[k] = t;
  }
  __syncthreads();
  int nd = dropN;
  for (int k = 0; k < nd; ++k)
    ((float4*)(out + (size_t)dropL[k] * Dd))[tid] = make_float4(0.f, 0.f, 0.f, 0.f);
}

// ------------- gather + cast dispatched tokens (etot-guarded) -------------
__global__ __launch_bounds__(256) void build_xg(
    const float* __restrict__ x, const int* __restrict__ smap,
    const int* __restrict__ etot, unsigned short* __restrict__ Xg) {
  int row = blockIdx.x;
  int e = row >> 11, p = row & (CAP - 1);
  int t = (p < etot[e]) ? smap[row] : -1;
  int j = threadIdx.x;
  float4 v = make_float4(0.f, 0.f, 0.f, 0.f);
  if (t >= 0) v = ((const float4*)(x + (size_t)t * Dd))[j];
  ushort4 o;
  o.x = f2bf(v.x); o.y = f2bf(v.y); o.z = f2bf(v.z); o.w = f2bf(v.w);
  ((ushort4*)(Xg + (size_t)row * Dd))[j] = o;
}

// ------------- 256^2-tile bf16 MFMA GEMM (B^T), counted-vmcnt dbuf (r6) -----
// 8 waves (2M x 4N), per-wave 128x64, BK=64, dbuf LDS, 0-conflict XOR layout.
// Staging split P0/P1/P2; waits vmcnt(4)@P1, vmcnt(2)@P3; never 0 in steady
// loop. Counted lgkm 8/4/4/0. Converged: 810 TF (90% of 2-barrier ceiling).
// DO_W2T: blocks z>=8 are w2-transpose riders (BW work in GEMM1's HBM slack);
// they reuse the LDS allocation and exit before the GEMM path.
template <int DO_GELU, int FUSE_COMBINE, int DO_W2T>
__global__ __launch_bounds__(512, 2) void gemm256_kernel(
    const unsigned short* __restrict__ A,   // [E][M][K] bf16
    const unsigned short* __restrict__ BT,  // [E][N][K] bf16
    unsigned short* __restrict__ Hout,      // [E][M][N] bf16 (GEMM1)
    const int* __restrict__ smap,           // [E][CAP] token map (GEMM2)
    const int* __restrict__ etot,           // [E] expert totals (GEMM2)
    const float* __restrict__ gate,         // [T]
    float* __restrict__ out,                // [T][D]
    const float* __restrict__ w2src,        // fp32 w2 (GEMM1 rider)
    unsigned short* __restrict__ W2Tdst,    // bf16 W2T (GEMM1 rider)
    int M, int N, int K) {
  __shared__ unsigned short lds[2][2][16384];  // [buf][A/B][256 rows x 64 k]
  int tid = threadIdx.x, lane = tid & 63, w = tid >> 6;

  if (DO_W2T && blockIdx.z >= 8) {
    // ---- w2 transpose tile: W2T[e][n][k] = w2[e][k][n], n over Dd, k over DFF
    int tz = ((int)blockIdx.z - 8) * 128 + (int)blockIdx.y * 16 + (int)blockIdx.x;
    int ze = tz >> 10, tile = tz & 1023;  // per expert: 64 row-tiles x 16 col-tiles
    const float* s = w2src + (size_t)ze * DFFf * Dd;
    unsigned short* d2 = W2Tdst + (size_t)ze * DFFf * Dd;
    int rb = (tile >> 4) * 64, cb = (tile & 15) * 64;
    float (*tl)[65] = (float(*)[65])(void*)lds;
    int c4 = (tid & 15) * 4;
    int r4 = tid >> 4;  // 0..31
#pragma unroll
    for (int i = 0; i < 2; ++i) {
      int r = r4 + i * 32;
      float4 v = *(const float4*)(s + (size_t)(rb + r) * Dd + cb + c4);
      tl[r][c4 + 0] = v.x; tl[r][c4 + 1] = v.y;
      tl[r][c4 + 2] = v.z; tl[r][c4 + 3] = v.w;
    }
    __syncthreads();
#pragma unroll
    for (int p = 0; p < 2; ++p) {
      int rr = r4 + p * 32;
      ushort4 o;
      o.x = f2bf(tl[c4 + 0][rr]);
      o.y = f2bf(tl[c4 + 1][rr]);
      o.z = f2bf(tl[c4 + 2][rr]);
      o.w = f2bf(tl[c4 + 3][rr]);
      *(ushort4*)(d2 + (size_t)(cb + rr) * DFFf + rb + c4) = o;
    }
    return;
  }

  int wm = w >> 2, wn = w & 3;
  // bijective XCD-aware swizzle over the GEMM sub-grid only (gz = 8)
  int gx = gridDim.x, gy = gridDim.y;
  long gid = blockIdx.x + (long)gx * (blockIdx.y + (long)gy * blockIdx.z);
  int nT = gx * gy * 8;
  int cpx = nT >> 3;
  int swz = (int)((gid & 7) * (long)cpx + (gid >> 3));
  int bn = swz % gx;
  int bm = (swz / gx) % gy;
  int e  = swz / (gx * gy);

  const unsigned short* Ab = A + ((size_t)e * M + (size_t)bm * 256) * K;
  const unsigned short* Bb = BT + ((size_t)e * N + (size_t)bn * 256) * K;

  // phys p holds logical p ^ (((p>>7)&7)<<4) (involution, both-sides swizzle)
  auto stageB = [&](const unsigned short* src, unsigned short* L, int h) {
#pragma unroll
    for (int q = 0; q < 2; ++q) {
      int p = h * 16384 + q * 8192 + tid * 16;
      int lg = p ^ (((p >> 7) & 7) << 4);
      gld16(src + (size_t)(lg >> 7) * K + ((lg & 127) >> 1),
            (unsigned short*)((char*)L + p));
    }
  };
  auto stageA = [&](const unsigned short* src, unsigned short* L, int h) {
#pragma unroll
    for (int q = 0; q < 2; ++q) {
      int p = q * 16384 + h * 8192 + tid * 16;
      int lg = p ^ (((p >> 7) & 7) << 4);
      gld16(src + (size_t)(lg >> 7) * K + ((lg & 127) >> 1),
            (unsigned short*)((char*)L + p));
    }
  };

  f32x4 acc[2][4][4];
#pragma unroll
  for (int mh = 0; mh < 2; ++mh)
#pragma unroll
    for (int mi = 0; mi < 4; ++mi)
#pragma unroll
      for (int n = 0; n < 4; ++n) acc[mh][mi][n] = (f32x4){0.f, 0.f, 0.f, 0.f};

  auto mfma16 = [&](f32x4 (*ac)[4], const bf16x8* av, const bf16x8* bv) {
#pragma unroll
    for (int mi = 0; mi < 4; ++mi)
#pragma unroll
      for (int n = 0; n < 4; ++n)
        ac[mi][n] = __builtin_amdgcn_mfma_f32_16x16x32_bf16(av[mi], bv[n], ac[mi][n], 0, 0, 0);
  };

  unsigned lbase = (unsigned)(size_t)(__attribute__((address_space(3))) unsigned short*)&lds[0][0][0];
  int arow = wm * 128 + (lane & 15);
  int brow = wn * 64 + (lane & 15);
  unsigned kc2 = (unsigned)(((lane >> 4) << 3) << 1);
  unsigned swA = (unsigned)((arow & 7) << 4), swB = (unsigned)((brow & 7) << 4);
  unsigned ak0 = lbase + ((((unsigned)arow << 7) + kc2) ^ swA);
  unsigned ak1 = lbase + ((((unsigned)arow << 7) + 64 + kc2) ^ swA);
  unsigned bk0 = lbase + 32768u + ((((unsigned)brow << 7) + kc2) ^ swB);
  unsigned bk1 = lbase + 32768u + ((((unsigned)brow << 7) + 64 + kc2) ^ swB);

  bf16x8 a0[4], a1[4], a2[4], a3[4], b0[4], b1[4];
#define G0_ { \
    b0[0] = dsr<0>(bk0); b0[1] = dsr<2048>(bk0); b0[2] = dsr<4096>(bk0); b0[3] = dsr<6144>(bk0); \
    a0[0] = dsr<0>(ak0); a0[1] = dsr<2048>(ak0); a0[2] = dsr<4096>(ak0); a0[3] = dsr<6144>(ak0); }
#define G1_ { \
    b1[0] = dsr<0>(bk1); b1[1] = dsr<2048>(bk1); b1[2] = dsr<4096>(bk1); b1[3] = dsr<6144>(bk1); \
    a1[0] = dsr<0>(ak1); a1[1] = dsr<2048>(ak1); a1[2] = dsr<4096>(ak1); a1[3] = dsr<6144>(ak1); }
#define G2_ { \
    a2[0] = dsr<8192>(ak0); a2[1] = dsr<10240>(ak0); a2[2] = dsr<12288>(ak0); a2[3] = dsr<14336>(ak0); }
#define G3_ { \
    a3[0] = dsr<8192>(ak1); a3[1] = dsr<10240>(ak1); a3[2] = dsr<12288>(ak1); a3[3] = dsr<14336>(ak1); }
#define SB0 __builtin_amdgcn_sched_barrier(0)
#define PRIO_MFMA(AC, AV, BV) { \
    __builtin_amdgcn_s_setprio(1); mfma16(AC, AV, BV); __builtin_amdgcn_s_setprio(0); }

  int NT = K >> 6;
  stageB(Bb, lds[0][1], 0); stageB(Bb, lds[0][1], 1);
  stageA(Ab, lds[0][0], 0);
  stageA(Ab, lds[0][0], 1);
  VMCNT(2);
  __builtin_amdgcn_s_barrier();
  G0_

  for (int t = 0; t < NT - 1; ++t) {
    unsigned short* SA = lds[(t & 1) ^ 1][0];
    unsigned short* SB = lds[(t & 1) ^ 1][1];
    const unsigned short* An = Ab + ((t + 1) << 6);
    const unsigned short* Bn = Bb + ((t + 1) << 6);
    // ---- P0: reads G1; stage B(t+1); wait G0; MFMA a0xb0 ----
    G1_
    stageB(Bn, SB, 0); stageB(Bn, SB, 1);
    LGKM(8); SB0;
    PRIO_MFMA(acc[0], a0, b0);
    // ---- P1: drain A-h1(t); reads G2; stage A-h0(t+1); wait G1; MFMA a1xb1 ----
    VMCNT(4);
    __builtin_amdgcn_s_barrier();
    G2_
    stageA(An, SA, 0);
    LGKM(4); SB0;
    PRIO_MFMA(acc[0], a1, b1);
    // ---- P2: reads G3; stage A-h1(t+1); wait G2; MFMA a2xb0 ----
    G3_
    stageA(An, SA, 1);
    LGKM(4); SB0;
    PRIO_MFMA(acc[1], a2, b0);
    // ---- P3: wait G3; MFMA a3xb1; drain B+A-h0(t+1); swap; reads G0 ----
    LGKM(0); SB0;
    PRIO_MFMA(acc[1], a3, b1);
    VMCNT(2);
    __builtin_amdgcn_s_barrier();
    ak0 ^= 65536u; ak1 ^= 65536u; bk0 ^= 65536u; bk1 ^= 65536u;
    G0_
  }

  // ---- final tile: no staging; single vmcnt(0) at P1 ----
  G1_
  LGKM(8); SB0;
  PRIO_MFMA(acc[0], a0, b0);
  VMCNT(0);
  __builtin_amdgcn_s_barrier();
  G2_
  LGKM(4); SB0;
  PRIO_MFMA(acc[0], a1, b1);
  G3_
  LGKM(4); SB0;
  PRIO_MFMA(acc[1], a2, b0);
  LGKM(0); SB0;
  PRIO_MFMA(acc[1], a3, b1);

#undef G0_
#undef G1_
#undef G2_
#undef G3_
#undef SB0
#undef PRIO_MFMA

  // ---- epilogue ----
  int r0 = bm * 256 + wm * 128;
  int c0 = bn * 256 + wn * 64;
#pragma unroll
  for (int mh = 0; mh < 2; ++mh)
#pragma unroll
    for (int mi = 0; mi < 4; ++mi) {
      int rowb = r0 + mh * 64 + mi * 16 + ((lane >> 4) << 2);
#pragma unroll
      for (int r = 0; r < 4; ++r) {
        int row = rowb + r;
        if (DO_GELU) {
#pragma unroll
          for (int n = 0; n < 4; ++n) {
            int col = c0 + n * 16 + (lane & 15);
            Hout[((size_t)e * M + row) * N + col] = f2bf(gelu_tanh(acc[mh][mi][n][r]));
          }
        }
        if (FUSE_COMBINE) {
          int tkn = (row < etot[e]) ? smap[e * CAP + row] : -1;
          if (tkn >= 0) {
            float g = gate[tkn];
#pragma unroll
            for (int n = 0; n < 4; ++n) {
              int col = c0 + n * 16 + (lane & 15);
              out[(size_t)tkn * Dd + col] = acc[mh][mi][n][r] * g;
            }
          }
        }
      }
    }
}

extern "C" void kernel_launch(void* const* d_in, const int* in_sizes, int n_in,
                              void* d_out, int out_size, void* d_ws, size_t ws_size,
                              hipStream_t stream) {
  const float* x  = (const float*)d_in[0];
  const float* wg = (const float*)d_in[1];
  const float* w1 = (const float*)d_in[2];
  const float* w2 = (const float*)d_in[3];
  float* out = (float*)d_out;

  char* ws = (char*)d_ws;
  int*   idx  = (int*)(ws + 0);
  float* gate = (float*)(ws + 131072);
  float* meP  = (float*)(ws + 196608);
  int*   smap = (int*)(ws + 327680);
  int*   cnt  = (int*)(ws + 393216);
  int*   base = (int*)(ws + 395264);
  int*   etot = (int*)(ws + 397312);
  unsigned short* Xg  = (unsigned short*)(ws + 401408ull);
  unsigned short* W1T = (unsigned short*)(ws + 33955840ull);
  unsigned short* W2T = (unsigned short*)(ws + 101064704ull);
  unsigned short* H   = (unsigned short*)(ws + 168173568ull);

  gating_w1t_kernel<<<12288, 256, 0, stream>>>(x, wg, w1, idx, gate, meP, W1T);
  count_kernel<<<Tt / 256, 256, 0, stream>>>(idx, cnt);
  prefix_kernel<<<1, 256, 0, stream>>>(cnt, base, meP, out + (size_t)Tt * Dd, etot);
  assign_kernel<<<Tt / 256, 256, 0, stream>>>(idx, base, smap, out);
  build_xg<<<Ee * CAP, 256, 0, stream>>>(x, smap, etot, Xg);
  gemm256_kernel<1, 0, 1><<<dim3(DFFf / 256, CAP / 256, 72), 512, 0, stream>>>(
      Xg, W1T, H, nullptr, nullptr, nullptr, nullptr, w2, W2T, CAP, DFFf, Dd);
  gemm256_kernel<0, 1, 0><<<dim3(Dd / 256, CAP / 256, 8), 512, 0, stream>>>(
      H, W2T, nullptr, smap, etot, gate, out, nullptr, nullptr, CAP, Dd, DFFf);
}